// Round 3
// baseline (1418.230 us; speedup 1.0000x reference)
//
#include <hip/hip_runtime.h>

#define EPSV 1e-5f
#define STS 1536  // floats per stats copy (replicated accumulators)

typedef short bf16x8 __attribute__((ext_vector_type(8)));
typedef float f32x4  __attribute__((ext_vector_type(4)));
#define MFMA_B16(a,b,c) __builtin_amdgcn_mfma_f32_16x16x32_bf16(a,b,c,0,0,0)

__device__ __forceinline__ unsigned short f2bf(float x){
  unsigned u = __float_as_uint(x);
  return (unsigned short)((u + 0x7fffu + ((u >> 16) & 1u)) >> 16);
}
__device__ __forceinline__ float bf2f(unsigned short h){ return __uint_as_float((unsigned)h << 16); }

__device__ __forceinline__ float fsig(float x){ return 1.0f / (1.0f + __expf(-x)); }
__device__ __forceinline__ float ftanh(float x){ return 1.0f - 2.0f / (__expf(2.0f * x) + 1.0f); }

// ---------------- Weight prep: fp32 -> bf16 into d_ws at byte 0.
// Layout (ushort idx): [0,4096) Wc4; [4096,8192) W2d4; [8192,12288) W3d4; [12288,16384) Wat4; [16384,49152) W5
__global__ __launch_bounds__(256) void k_wprep(
    const float* __restrict__ wc4, const float* __restrict__ w2d4,
    const float* __restrict__ w3d4, const float* __restrict__ wat4,
    const float* __restrict__ w5, unsigned short* __restrict__ wbf)
{
  int i = (blockIdx.x * 256 + threadIdx.x) * 4;
  const float* src; int base;
  if      (i < 4096){  src = wc4;  base = 0; }
  else if (i < 8192){  src = w2d4; base = 4096; }
  else if (i < 12288){ src = w3d4; base = 8192; }
  else if (i < 16384){ src = wat4; base = 12288; }
  else              {  src = w5;   base = 16384; }
  float4 v = *(const float4*)(src + (i - base));
  ushort4 o;
  o.x = f2bf(v.x); o.y = f2bf(v.y); o.z = f2bf(v.z); o.w = f2bf(v.w);
  *(ushort4*)(wbf + i) = o;
}

// ---------------- Dedicated BN-stats kernel: per-channel sum/sumsq of u [N,C] fp32.
template<int C>
__global__ __launch_bounds__(256) void k_stats(
    const float* __restrict__ u, float* __restrict__ gS, float* __restrict__ gQ,
    int ncopy, int N)
{
  const int tid = threadIdx.x;
  constexpr int PH = C / 4;     // float4 phases per row; 256 % PH == 0 so phase is fixed per thread
  __shared__ float sS[C], sQ[C];
  if (tid < C){ sS[tid] = 0.f; sQ[tid] = 0.f; }
  __syncthreads();

  const size_t total4 = (size_t)N * PH;
  size_t idx = (size_t)blockIdx.x * 256 + tid;
  const size_t stride = (size_t)gridDim.x * 256;
  const float4* up = (const float4*)u;
  float4 s = make_float4(0.f,0.f,0.f,0.f), q = make_float4(0.f,0.f,0.f,0.f);
  for (; idx < total4; idx += stride){
    float4 v = up[idx];
    s.x += v.x; s.y += v.y; s.z += v.z; s.w += v.w;
    q.x += v.x*v.x; q.y += v.y*v.y; q.z += v.z*v.z; q.w += v.w*v.w;
  }
  #pragma unroll
  for (int m = PH; m < 64; m <<= 1){
    s.x += __shfl_xor(s.x, m, 64); s.y += __shfl_xor(s.y, m, 64);
    s.z += __shfl_xor(s.z, m, 64); s.w += __shfl_xor(s.w, m, 64);
    q.x += __shfl_xor(q.x, m, 64); q.y += __shfl_xor(q.y, m, 64);
    q.z += __shfl_xor(q.z, m, 64); q.w += __shfl_xor(q.w, m, 64);
  }
  if ((tid & 63) < PH){
    const int cb = (tid & (PH - 1)) * 4;
    atomicAdd(&sS[cb+0], s.x); atomicAdd(&sS[cb+1], s.y);
    atomicAdd(&sS[cb+2], s.z); atomicAdd(&sS[cb+3], s.w);
    atomicAdd(&sQ[cb+0], q.x); atomicAdd(&sQ[cb+1], q.y);
    atomicAdd(&sQ[cb+2], q.z); atomicAdd(&sQ[cb+3], q.w);
  }
  __syncthreads();
  if (tid < C){
    const int co = (blockIdx.x & (ncopy - 1)) * STS;
    atomicAdd(&gS[co + tid], sS[tid]); atomicAdd(&gQ[co + tid], sQ[tid]);
  }
}

// ---------------- Stage 1: points -> lin1(6->8)+relu -> fuse(C=8) -> u1 [N,16]. Pure streaming.
// Weights staged to LDS (broadcast ds_read) to dodge s_load+lgkmcnt serialization.
__global__ __launch_bounds__(256) void k_stage1(
    const float* __restrict__ pts, const float* __restrict__ f2d,
    const float* __restrict__ Wc, const float* __restrict__ bc,
    const float* __restrict__ W2d, const float* __restrict__ b2d,
    const float* __restrict__ W3d, const float* __restrict__ b3d,
    const float* __restrict__ Watt, const float* __restrict__ batt,
    float* __restrict__ uout, int N)
{
  const int tid = threadIdx.x;
  __shared__ float sW1[48], s2d[64], s3d[64], sat[64];
  if (tid < 48)                 sW1[tid]       = Wc[tid];
  if (tid >= 64  && tid < 128)  s2d[tid - 64]  = W2d[tid - 64];
  if (tid >= 128 && tid < 192)  s3d[tid - 128] = W3d[tid - 128];
  if (tid >= 192)               sat[tid - 192] = Watt[tid - 192];
  __syncthreads();

  const int n = blockIdx.x * 256 + tid;
  if (n >= N) return;
  const size_t nc = (size_t)n;

  const float* p = pts + nc * 10;
  float xin[6];
  xin[0]=p[0]; xin[1]=p[1]; xin[2]=p[2]; xin[3]=p[7]; xin[4]=p[8]; xin[5]=p[9];
  float x1[8];
  #pragma unroll
  for (int i = 0; i < 8; i++){
    float a = bc[i];
    #pragma unroll
    for (int j = 0; j < 6; j++) a = fmaf(sW1[i*6+j], xin[j], a);
    x1[i] = fmaxf(a, 0.f);
  }
  float f[8];
  { const float4* fp4 = (const float4*)(f2d + nc * 8);
    float4 t0 = fp4[0], t1 = fp4[1];
    f[0]=t0.x; f[1]=t0.y; f[2]=t0.z; f[3]=t0.w;
    f[4]=t1.x; f[5]=t1.y; f[6]=t1.z; f[7]=t1.w; }
  float d2d[8];
  #pragma unroll
  for (int i = 0; i < 8; i++){
    const float4* w = (const float4*)(s2d + i*8);
    float4 w0 = w[0], w1 = w[1];
    float a = b2d[i];
    a = fmaf(w0.x, f[0], a); a = fmaf(w0.y, f[1], a);
    a = fmaf(w0.z, f[2], a); a = fmaf(w0.w, f[3], a);
    a = fmaf(w1.x, f[4], a); a = fmaf(w1.y, f[5], a);
    a = fmaf(w1.z, f[6], a); a = fmaf(w1.w, f[7], a);
    d2d[i] = a;
  }
  float mid[8];
  #pragma unroll
  for (int i = 0; i < 8; i++){
    const float4* w = (const float4*)(s3d + i*8);
    float4 w0 = w[0], w1 = w[1];
    float a = b3d[i] + d2d[i];
    a = fmaf(w0.x, x1[0], a); a = fmaf(w0.y, x1[1], a);
    a = fmaf(w0.z, x1[2], a); a = fmaf(w0.w, x1[3], a);
    a = fmaf(w1.x, x1[4], a); a = fmaf(w1.y, x1[5], a);
    a = fmaf(w1.z, x1[6], a); a = fmaf(w1.w, x1[7], a);
    mid[i] = ftanh(a);
  }
  float r[8];
  #pragma unroll
  for (int i = 0; i < 8; i++){
    const float4* w = (const float4*)(sat + i*8);
    float4 w0 = w[0], w1 = w[1];
    float a = batt[i];
    a = fmaf(w0.x, mid[0], a); a = fmaf(w0.y, mid[1], a);
    a = fmaf(w0.z, mid[2], a); a = fmaf(w0.w, mid[3], a);
    a = fmaf(w1.x, mid[4], a); a = fmaf(w1.y, mid[5], a);
    a = fmaf(w1.z, mid[6], a); a = fmaf(w1.w, mid[7], a);
    r[i] = fsig(a) * d2d[i];
  }
  float* urow = uout + nc * 16;
  *(float4*)(urow + 0)  = make_float4(x1[0], x1[1], x1[2], x1[3]);
  *(float4*)(urow + 4)  = make_float4(x1[4], x1[5], x1[6], x1[7]);
  *(float4*)(urow + 8)  = make_float4(r[0], r[1], r[2], r[3]);
  *(float4*)(urow + 12) = make_float4(r[4], r[5], r[6], r[7]);
}

// ---------------- Scalar mid stage (C=16, C=32). Streaming; weights staged to LDS.
template<int C>
__global__ __launch_bounds__(256) void k_stage(
    const float* __restrict__ uprev, const float* __restrict__ pS, const float* __restrict__ pQ,
    const float* __restrict__ gam, const float* __restrict__ bet,
    const float* __restrict__ Wc, const float* __restrict__ bc,
    const float* __restrict__ f2d,
    const float* __restrict__ W2d, const float* __restrict__ b2d,
    const float* __restrict__ W3d, const float* __restrict__ b3d,
    const float* __restrict__ Watt, const float* __restrict__ batt,
    float* __restrict__ uout, int ncopy, float invN, int N)
{
  const int tid = threadIdx.x;
  __shared__ float sA[C], sB[C];
  __shared__ float sWc[C*C], sW2[C*C], sW3[C*C], sWa[C*C];
  {
    constexpr int NV = C * C / 4;   // float4 words per matrix: 64 (C=16), 256 (C=32)
    for (int i = tid; i < NV; i += 256){
      ((float4*)sWc)[i] = ((const float4*)Wc)[i];
      ((float4*)sW2)[i] = ((const float4*)W2d)[i];
      ((float4*)sW3)[i] = ((const float4*)W3d)[i];
      ((float4*)sWa)[i] = ((const float4*)Watt)[i];
    }
  }
  if (tid < C){
    float s = 0.f, q = 0.f;
    for (int c = 0; c < ncopy; c++){ s += pS[c*STS + tid]; q += pQ[c*STS + tid]; }
    float m = s * invN;
    float v = q * invN - m * m;
    float a = gam[tid] * rsqrtf(v + EPSV);
    sA[tid] = a; sB[tid] = fmaf(-a, m, bet[tid]);
  }
  __syncthreads();

  const int n = blockIdx.x * 256 + tid;
  if (n >= N) return;
  const size_t nc = (size_t)n;

  float y[C];
  { const float4* up4 = (const float4*)(uprev + nc * C);
    #pragma unroll
    for (int j = 0; j < C; j += 4){
      float4 t = up4[j >> 2];
      y[j+0] = fmaf(sA[j+0], t.x, sB[j+0]);
      y[j+1] = fmaf(sA[j+1], t.y, sB[j+1]);
      y[j+2] = fmaf(sA[j+2], t.z, sB[j+2]);
      y[j+3] = fmaf(sA[j+3], t.w, sB[j+3]);
    } }
  float x[C];
  #pragma unroll
  for (int i = 0; i < C; i++){
    const float4* w = (const float4*)(sWc + i * C);
    float a0 = bc[i], a1 = 0.f, a2 = 0.f, a3 = 0.f;
    #pragma unroll
    for (int j = 0; j < C/4; j++){
      float4 wv = w[j];
      a0 = fmaf(wv.x, y[4*j+0], a0); a1 = fmaf(wv.y, y[4*j+1], a1);
      a2 = fmaf(wv.z, y[4*j+2], a2); a3 = fmaf(wv.w, y[4*j+3], a3);
    }
    x[i] = fmaxf((a0 + a1) + (a2 + a3), 0.f);
  }
  float* urow = uout + nc * (2 * C);
  #pragma unroll
  for (int i = 0; i < C; i += 4)
    *(float4*)(urow + i) = make_float4(x[i], x[i+1], x[i+2], x[i+3]);

  float f[C];
  { const float4* fp4 = (const float4*)(f2d + nc * C);
    #pragma unroll
    for (int j = 0; j < C; j += 4){
      float4 t = fp4[j >> 2];
      f[j+0]=t.x; f[j+1]=t.y; f[j+2]=t.z; f[j+3]=t.w;
    } }
  float d2d[C];
  #pragma unroll
  for (int i = 0; i < C; i++){
    const float4* w = (const float4*)(sW2 + i * C);
    float a0 = b2d[i], a1 = 0.f, a2 = 0.f, a3 = 0.f;
    #pragma unroll
    for (int j = 0; j < C/4; j++){
      float4 wv = w[j];
      a0 = fmaf(wv.x, f[4*j+0], a0); a1 = fmaf(wv.y, f[4*j+1], a1);
      a2 = fmaf(wv.z, f[4*j+2], a2); a3 = fmaf(wv.w, f[4*j+3], a3);
    }
    d2d[i] = (a0 + a1) + (a2 + a3);
  }
  float mid[C];
  #pragma unroll
  for (int i = 0; i < C; i++){
    const float4* w = (const float4*)(sW3 + i * C);
    float a0 = b3d[i] + d2d[i], a1 = 0.f, a2 = 0.f, a3 = 0.f;
    #pragma unroll
    for (int j = 0; j < C/4; j++){
      float4 wv = w[j];
      a0 = fmaf(wv.x, x[4*j+0], a0); a1 = fmaf(wv.y, x[4*j+1], a1);
      a2 = fmaf(wv.z, x[4*j+2], a2); a3 = fmaf(wv.w, x[4*j+3], a3);
    }
    mid[i] = ftanh((a0 + a1) + (a2 + a3));
  }
  #pragma unroll
  for (int i = 0; i < C; i++){
    const float4* w = (const float4*)(sWa + i * C);
    float a0 = batt[i], a1 = 0.f, a2 = 0.f, a3 = 0.f;
    #pragma unroll
    for (int j = 0; j < C/4; j++){
      float4 wv = w[j];
      a0 = fmaf(wv.x, mid[4*j+0], a0); a1 = fmaf(wv.y, mid[4*j+1], a1);
      a2 = fmaf(wv.z, mid[4*j+2], a2); a3 = fmaf(wv.w, mid[4*j+3], a3);
    }
    x[i] = fsig((a0 + a1) + (a2 + a3)) * d2d[i];
  }
  #pragma unroll
  for (int i = 0; i < C; i += 4)
    *(float4*)(urow + C + i) = make_float4(x[i], x[i+1], x[i+2], x[i+3]);
}

// ---------------- Stage 4 MFMA (C=64): persistent grid, register stat accumulation across chunks
__global__ __launch_bounds__(256) void k_stage4_mfma(
    const float* __restrict__ u3, const float* __restrict__ pS, const float* __restrict__ pQ,
    const float* __restrict__ gam, const float* __restrict__ bet,
    const float* __restrict__ f2d,
    const unsigned short* __restrict__ wbf,   // wc4@0, w2d4@4096, w3d4@8192, wat4@12288
    const float* __restrict__ bc, const float* __restrict__ b2d,
    const float* __restrict__ b3d, const float* __restrict__ batt,
    unsigned short* __restrict__ u4o, float* __restrict__ gS, float* __restrict__ gQ,
    int ncopy, float invN, int N)
{
  const int tid = threadIdx.x;
  __shared__ float sA[64], sB[64];
  __shared__ unsigned short yb[64*72], fb[64*72], xb[64*72], mb[64*72], rb[64*72];

  if (tid < 64){
    float s = 0.f, q = 0.f;
    for (int c = 0; c < ncopy; c++){ s += pS[c*STS + tid]; q += pQ[c*STS + tid]; }
    float m = s * invN;
    float v = q * invN - m * m;
    float a = gam[tid] * rsqrtf(v + EPSV);
    sA[tid] = a; sB[tid] = fmaf(-a, m, bet[tid]);
  }
  __syncthreads();

  const int w = tid >> 6;
  const int lane = tid & 63;
  const int cN = lane & 15;
  const int q = lane >> 4;

  bf16x8 aWc[2], aW2[2], aW3[2], aWa[2];
  #pragma unroll
  for (int kc = 0; kc < 2; kc++){
    size_t off = (size_t)(w*16 + cN) * 64 + kc*32 + q*8;
    aWc[kc] = *(const bf16x8*)(wbf + off);
    aW2[kc] = *(const bf16x8*)(wbf + 4096 + off);
    aW3[kc] = *(const bf16x8*)(wbf + 8192 + off);
    aWa[kc] = *(const bf16x8*)(wbf + 12288 + off);
  }
  f32x4 bbc = *(const f32x4*)(bc   + w*16 + q*4);
  f32x4 bb2 = *(const f32x4*)(b2d  + w*16 + q*4);
  f32x4 bb3 = *(const f32x4*)(b3d  + w*16 + q*4);
  f32x4 bba = *(const f32x4*)(batt + w*16 + q*4);

  #define BFRAG(buf, p, kc) (*(const bf16x8*)((buf) + ((p)*16 + cN)*72 + (kc)*32 + q*8))

  f32x4 ssx = {0,0,0,0}, qqx = {0,0,0,0};
  f32x4 ssr = {0,0,0,0}, qqr = {0,0,0,0};

  for (int pt0 = blockIdx.x * 64; pt0 < N; pt0 += gridDim.x * 64){
    {
      const int pt = tid >> 2;
      const int c16 = (tid & 3) << 4;
      const int gpt = pt0 + pt;
      const bool v = gpt < N;
      const float4* ur = (const float4*)(u3  + (size_t)(v ? gpt : 0) * 64 + c16);
      const float4* fr = (const float4*)(f2d + (size_t)(v ? gpt : 0) * 64 + c16);
      #pragma unroll
      for (int i = 0; i < 4; i++){
        float4 t = ur[i], ff = fr[i];
        float4 a = *(const float4*)(sA + c16 + 4*i);
        float4 b = *(const float4*)(sB + c16 + 4*i);
        float y0 = v ? fmaf(a.x, t.x, b.x) : 0.f;
        float y1 = v ? fmaf(a.y, t.y, b.y) : 0.f;
        float y2 = v ? fmaf(a.z, t.z, b.z) : 0.f;
        float y3 = v ? fmaf(a.w, t.w, b.w) : 0.f;
        uint2 yw, fw;
        yw.x = (unsigned)f2bf(y0) | ((unsigned)f2bf(y1) << 16);
        yw.y = (unsigned)f2bf(y2) | ((unsigned)f2bf(y3) << 16);
        fw.x = (unsigned)f2bf(v ? ff.x : 0.f) | ((unsigned)f2bf(v ? ff.y : 0.f) << 16);
        fw.y = (unsigned)f2bf(v ? ff.z : 0.f) | ((unsigned)f2bf(v ? ff.w : 0.f) << 16);
        *(uint2*)(yb + pt*72 + c16 + 4*i) = yw;
        *(uint2*)(fb + pt*72 + c16 + 4*i) = fw;
      }
    }
    __syncthreads();

    f32x4 d2d[4];
    #pragma unroll
    for (int p = 0; p < 4; p++){
      f32x4 acc = bb2;
      acc = MFMA_B16(aW2[0], BFRAG(fb, p, 0), acc);
      acc = MFMA_B16(aW2[1], BFRAG(fb, p, 1), acc);
      d2d[p] = acc;
    }
    #pragma unroll
    for (int p = 0; p < 4; p++){
      f32x4 acc = bbc;
      acc = MFMA_B16(aWc[0], BFRAG(yb, p, 0), acc);
      acc = MFMA_B16(aWc[1], BFRAG(yb, p, 1), acc);
      const bool vc = (pt0 + p*16 + cN) < N;
      #pragma unroll
      for (int r = 0; r < 4; r++){
        float z = fmaxf(acc[r], 0.f);
        acc[r] = z;
        float zm = vc ? z : 0.f;
        ssx[r] += zm; qqx[r] += zm * zm;
      }
      uint2 pk;
      pk.x = (unsigned)f2bf(acc[0]) | ((unsigned)f2bf(acc[1]) << 16);
      pk.y = (unsigned)f2bf(acc[2]) | ((unsigned)f2bf(acc[3]) << 16);
      *(uint2*)(xb + (p*16 + cN)*72 + w*16 + q*4) = pk;
    }
    __syncthreads();
    #pragma unroll
    for (int p = 0; p < 4; p++){
      f32x4 acc = bb3 + d2d[p];
      acc = MFMA_B16(aW3[0], BFRAG(xb, p, 0), acc);
      acc = MFMA_B16(aW3[1], BFRAG(xb, p, 1), acc);
      #pragma unroll
      for (int r = 0; r < 4; r++) acc[r] = ftanh(acc[r]);
      uint2 pk;
      pk.x = (unsigned)f2bf(acc[0]) | ((unsigned)f2bf(acc[1]) << 16);
      pk.y = (unsigned)f2bf(acc[2]) | ((unsigned)f2bf(acc[3]) << 16);
      *(uint2*)(mb + (p*16 + cN)*72 + w*16 + q*4) = pk;
    }
    __syncthreads();
    #pragma unroll
    for (int p = 0; p < 4; p++){
      f32x4 acc = bba;
      acc = MFMA_B16(aWa[0], BFRAG(mb, p, 0), acc);
      acc = MFMA_B16(aWa[1], BFRAG(mb, p, 1), acc);
      const bool vc = (pt0 + p*16 + cN) < N;
      #pragma unroll
      for (int r = 0; r < 4; r++){
        float rr = fsig(acc[r]) * d2d[p][r];
        acc[r] = rr;
        float zm = vc ? rr : 0.f;
        ssr[r] += zm; qqr[r] += zm * zm;
      }
      uint2 pk;
      pk.x = (unsigned)f2bf(acc[0]) | ((unsigned)f2bf(acc[1]) << 16);
      pk.y = (unsigned)f2bf(acc[2]) | ((unsigned)f2bf(acc[3]) << 16);
      *(uint2*)(rb + (p*16 + cN)*72 + w*16 + q*4) = pk;
    }
    __syncthreads();
    {
      const int pt = tid >> 2;
      const int quarter = tid & 3;
      const int gpt = pt0 + pt;
      if (gpt < N){
        const unsigned short* src = (quarter < 2 ? xb : rb) + pt*72 + (quarter & 1)*32;
        unsigned short* dst = u4o + (size_t)gpt * 128 + quarter*32;
        #pragma unroll
        for (int i = 0; i < 4; i++)
          *(uint4*)(dst + 8*i) = *(const uint4*)(src + 8*i);
      }
    }
  }

  const int co = (blockIdx.x & (ncopy - 1)) * STS;
  #pragma unroll
  for (int r = 0; r < 4; r++){
    float s = ssx[r], qq = qqx[r], s2 = ssr[r], q2 = qqr[r];
    #pragma unroll
    for (int m = 1; m < 16; m <<= 1){
      s  += __shfl_xor(s,  m, 64); qq += __shfl_xor(qq, m, 64);
      s2 += __shfl_xor(s2, m, 64); q2 += __shfl_xor(q2, m, 64);
    }
    if (cN == 0){
      int ch = w*16 + q*4 + r;
      atomicAdd(&gS[co + ch], s);       atomicAdd(&gQ[co + ch], qq);
      atomicAdd(&gS[co + 64 + ch], s2); atomicAdd(&gQ[co + 64 + ch], q2);
    }
  }
  #undef BFRAG
}

// ---------------- Stage 5 MFMA: persistent grid, register stat accumulation across chunks
__global__ __launch_bounds__(256) void k_stage5_mfma(
    const unsigned short* __restrict__ u4, const float* __restrict__ pS, const float* __restrict__ pQ,
    const float* __restrict__ gam, const float* __restrict__ bet,
    const unsigned short* __restrict__ w5bf, const float* __restrict__ b5,
    float* __restrict__ gS, float* __restrict__ gQ,
    int* __restrict__ gMx, int* __restrict__ gMn,
    int ncopy, float invN, int N)
{
  const int tid = threadIdx.x;
  __shared__ float sA[128], sB[128];
  __shared__ unsigned short yb[64*136];

  if (tid < 128){
    float s = 0.f, q = 0.f;
    for (int c = 0; c < ncopy; c++){ s += pS[c*STS + tid]; q += pQ[c*STS + tid]; }
    float m = s * invN;
    float v = q * invN - m * m;
    float a = gam[tid] * rsqrtf(v + EPSV);
    sA[tid] = a; sB[tid] = fmaf(-a, m, bet[tid]);
  }
  __syncthreads();

  const int w = tid >> 6;
  const int lane = tid & 63;
  const int cN = lane & 15;
  const int q = lane >> 4;

  bf16x8 aW[4][4];
  f32x4 bb[4];
  #pragma unroll
  for (int mg = 0; mg < 4; mg++){
    int m = (w*4 + mg)*16 + cN;
    #pragma unroll
    for (int kc = 0; kc < 4; kc++)
      aW[mg][kc] = *(const bf16x8*)(w5bf + (size_t)m*128 + kc*32 + q*8);
    bb[mg] = *(const f32x4*)(b5 + (w*4 + mg)*16 + q*4);
  }

  const float FINF = __int_as_float(0x7f800000);
  f32x4 s5[4], q5[4], mx5[4], mn5[4];
  #pragma unroll
  for (int mg = 0; mg < 4; mg++){
    s5[mg] = (f32x4){0,0,0,0}; q5[mg] = (f32x4){0,0,0,0};
    mx5[mg] = (f32x4){0,0,0,0};
    mn5[mg] = (f32x4){FINF, FINF, FINF, FINF};
  }

  for (int pt0 = blockIdx.x * 64; pt0 < N; pt0 += gridDim.x * 64){
    {
      const int pt = tid >> 2;
      const int t3 = tid & 3;
      const int c32 = t3 << 5;
      const int gpt = pt0 + pt;
      const bool v = gpt < N;
      const unsigned short* ur = u4 + (size_t)(v ? gpt : 0) * 128 + c32;
      #pragma unroll
      for (int ii = 0; ii < 4; ii++){
        const int i = (ii + t3) & 3;
        uint4 t = *(const uint4*)(ur + 8*i);
        const float* a = sA + c32 + 8*i;
        const float* b = sB + c32 + 8*i;
        unsigned tv[4] = {t.x, t.y, t.z, t.w};
        uint4 o;
        unsigned ov[4];
        #pragma unroll
        for (int k = 0; k < 4; k++){
          float v0 = v ? fmaf(a[2*k],   bf2f((unsigned short)(tv[k] & 0xffff)), b[2*k])   : 0.f;
          float v1 = v ? fmaf(a[2*k+1], bf2f((unsigned short)(tv[k] >> 16)),    b[2*k+1]) : 0.f;
          ov[k] = (unsigned)f2bf(v0) | ((unsigned)f2bf(v1) << 16);
        }
        o.x = ov[0]; o.y = ov[1]; o.z = ov[2]; o.w = ov[3];
        *(uint4*)(yb + pt*136 + c32 + 8*i) = o;
      }
    }
    __syncthreads();

    #pragma unroll
    for (int p = 0; p < 4; p++){
      bf16x8 B0 = *(const bf16x8*)(yb + (p*16 + cN)*136 + 0*32 + q*8);
      bf16x8 B1 = *(const bf16x8*)(yb + (p*16 + cN)*136 + 1*32 + q*8);
      bf16x8 B2 = *(const bf16x8*)(yb + (p*16 + cN)*136 + 2*32 + q*8);
      bf16x8 B3 = *(const bf16x8*)(yb + (p*16 + cN)*136 + 3*32 + q*8);
      const bool vc = (pt0 + p*16 + cN) < N;
      #pragma unroll
      for (int mg = 0; mg < 4; mg++){
        f32x4 acc = bb[mg];
        acc = MFMA_B16(aW[mg][0], B0, acc);
        acc = MFMA_B16(aW[mg][1], B1, acc);
        acc = MFMA_B16(aW[mg][2], B2, acc);
        acc = MFMA_B16(aW[mg][3], B3, acc);
        #pragma unroll
        for (int r = 0; r < 4; r++){
          float z = fmaxf(acc[r], 0.f);
          float zm = vc ? z : 0.f;
          s5[mg][r] += zm; q5[mg][r] += zm * zm;
          mx5[mg][r] = fmaxf(mx5[mg][r], zm);
          mn5[mg][r] = fminf(mn5[mg][r], vc ? z : FINF);
        }
      }
    }
    __syncthreads();
  }

  const int co = (blockIdx.x & (ncopy - 1)) * STS;
  #pragma unroll
  for (int mg = 0; mg < 4; mg++){
    #pragma unroll
    for (int r = 0; r < 4; r++){
      float s = s5[mg][r], qq = q5[mg][r], mx = mx5[mg][r], mn = mn5[mg][r];
      #pragma unroll
      for (int m = 1; m < 16; m <<= 1){
        s  += __shfl_xor(s,  m, 64); qq += __shfl_xor(qq, m, 64);
        mx = fmaxf(mx, __shfl_xor(mx, m, 64));
        mn = fminf(mn, __shfl_xor(mn, m, 64));
      }
      if (cN == 0){
        int ch = (w*4 + mg)*16 + q*4 + r;
        atomicAdd(&gS[co + ch], s); atomicAdd(&gQ[co + ch], qq);
        atomicMax(&gMx[co + ch], __float_as_int(mx));
        atomicMin(&gMn[co + ch], __float_as_int(mn));
      }
    }
  }
}

// ---------------- point_feature: out rows [256..320) = transpose(BN3(u3))
__global__ __launch_bounds__(256) void k_pf(
    const float* __restrict__ u3, const float* __restrict__ pS, const float* __restrict__ pQ,
    const float* __restrict__ gam, const float* __restrict__ bet,
    float* __restrict__ out, int ncopy, float invN, int N)
{
  const int tid = threadIdx.x;
  const int n0 = blockIdx.x * 64;
  __shared__ float sA[64], sB[64];
  __shared__ float T[64][68];
  if (tid < 64){
    float s = 0.f, q = 0.f;
    for (int c = 0; c < ncopy; c++){ s += pS[c*STS + tid]; q += pQ[c*STS + tid]; }
    float m = s * invN;
    float v = q * invN - m * m;
    float a = gam[tid] * rsqrtf(v + EPSV);
    sA[tid] = a; sB[tid] = fmaf(-a, m, bet[tid]);
  }
  __syncthreads();
  {
    const int r = tid >> 2;
    const int c16 = (tid & 3) << 4;
    const int gn = n0 + r;
    const bool v = gn < N;
    const float4* ur = (const float4*)(u3 + (size_t)(v ? gn : 0) * 64 + c16);
    #pragma unroll
    for (int i = 0; i < 4; i++){
      float4 t = ur[i];
      float4 a = *(const float4*)(sA + c16 + 4*i);
      float4 b = *(const float4*)(sB + c16 + 4*i);
      T[c16 + 4*i + 0][r] = v ? fmaf(a.x, t.x, b.x) : 0.f;
      T[c16 + 4*i + 1][r] = v ? fmaf(a.y, t.y, b.y) : 0.f;
      T[c16 + 4*i + 2][r] = v ? fmaf(a.z, t.z, b.z) : 0.f;
      T[c16 + 4*i + 3][r] = v ? fmaf(a.w, t.w, b.w) : 0.f;
    }
  }
  __syncthreads();
  {
    const int ch = tid >> 2;
    const int m16 = (tid & 3) << 4;
    #pragma unroll
    for (int i = 0; i < 4; i++){
      int nn = n0 + m16 + 4*i;
      if (nn < N)
        *(float4*)(out + (size_t)(256 + ch) * N + nn) = *(const float4*)(&T[ch][m16 + 4*i]);
    }
  }
}

// ---------------- Fill glob rows (sum/combine the ncopy stat copies)
__global__ __launch_bounds__(256) void k_fill(
    const float* __restrict__ gS, const float* __restrict__ gQ,
    const int* __restrict__ gMx, const int* __restrict__ gMn,
    const float* __restrict__ g5, const float* __restrict__ be5,
    float* __restrict__ out, int ncopy, float invN, int N)
{
  const int c = blockIdx.y;
  const float FINF = __int_as_float(0x7f800000);
  float s = 0.f, q = 0.f, zx = 0.f, zn = FINF;
  for (int cp = 0; cp < ncopy; cp++){
    s += gS[cp*STS + c]; q += gQ[cp*STS + c];
    zx = fmaxf(zx, __int_as_float(gMx[cp*STS + c]));
    zn = fminf(zn, __int_as_float(gMn[cp*STS + c]));
  }
  float m = s * invN;
  float v = q * invN - m * m;
  float a = g5[c] * rsqrtf(v + EPSV);
  float d = fmaf(-a, m, be5[c]);
  float glob = (a >= 0.f) ? fmaf(a, zx, d) : fmaf(a, zn, d);
  int n0 = (blockIdx.x * 256 + threadIdx.x) * 8;
  float4 gv = make_float4(glob, glob, glob, glob);
  if (n0 < N)     *(float4*)(out + (size_t)c * N + n0)     = gv;
  if (n0 + 4 < N) *(float4*)(out + (size_t)c * N + n0 + 4) = gv;
}

extern "C" void kernel_launch(void* const* d_in, const int* in_sizes, int n_in,
                              void* d_out, int out_size, void* d_ws, size_t ws_size,
                              hipStream_t stream) {
  const int N = in_sizes[0] / 10;
  auto F = [&](int i){ return (const float*)d_in[i]; };
  const float* P  = F(0);
  const float* F1 = F(1); const float* F2 = F(2); const float* F3 = F(3); const float* F4 = F(4);
  const float* Wc1 = F(5);  const float* Bc1 = F(6);
  const float* Wc2 = F(7);  const float* Bc2 = F(8);
  const float* Wc3 = F(9);  const float* Bc3 = F(10);
  const float* Wc4 = F(11); const float* Bc4 = F(12);
  const float* Wc5 = F(13); const float* Bc5 = F(14);
  const float* G1 = F(15); const float* BE1 = F(16);
  const float* G2 = F(17); const float* BE2 = F(18);
  const float* G3 = F(19); const float* BE3 = F(20);
  const float* G4 = F(21); const float* BE4 = F(22);
  const float* G5 = F(23); const float* BE5 = F(24);
  const float *W2d1=F(25), *B2d1=F(26), *W3d1=F(27), *B3d1=F(28), *Wat1=F(29), *Bat1=F(30);
  const float *W2d2=F(31), *B2d2=F(32), *W3d2=F(33), *B3d2=F(34), *Wat2=F(35), *Bat2=F(36);
  const float *W2d3=F(37), *B2d3=F(38), *W3d3=F(39), *B3d3=F(40), *Wat3=F(41), *Bat3=F(42);
  const float *W2d4=F(43), *B2d4=F(44), *W3d4=F(45), *B3d4=F(46), *Wat4=F(47), *Bat4=F(48);

  float* out = (float*)d_out;
  // Scratch aliased into the glob region of the output (rows 0..255, written last by k_fill).
  float* u1 = out;                                   // [N,16] fp32
  float* u2 = u1 + (size_t)N * 16;                   // [N,32] fp32
  float* u3 = u2 + (size_t)N * 32;                   // [N,64] fp32  (ends at 112N)
  unsigned short* u4 = (unsigned short*)(out + (size_t)N * 112);  // [N,128] bf16 (64N floats worth)

  // d_ws layout: bf16 weights at byte 0 (49152 ushorts = 96 KiB), then ncopy stat copies of STS floats.
  unsigned short* wbf = (unsigned short*)d_ws;
  float* st = (float*)((char*)d_ws + 98304);
  const int ncopy = (ws_size >= (size_t)98304 + 8u * STS * sizeof(float)) ? 8 : 1;
  float* S1 = st;        float* Q1 = st + 16;
  float* S2 = st + 32;   float* Q2 = st + 64;
  float* S3 = st + 96;   float* Q3 = st + 160;
  float* S4 = st + 224;  float* Q4 = st + 352;
  float* S5 = st + 480;  float* Q5 = st + 736;
  int*   MX = (int*)(st + 992);
  int*   MN = (int*)(st + 1248);
  hipMemsetAsync(st, 0, (size_t)ncopy * STS * sizeof(float), stream);
  for (int c = 0; c < ncopy; c++)
    hipMemsetAsync(MN + c * STS, 0x7f, 256 * sizeof(float), stream);  // +large float

  const int nb = (N + 255) / 256;
  const int nb64 = (N + 63) / 64;
  const float invN = 1.0f / (float)N;
  int NB4 = 768;  if (NB4 > nb64) NB4 = nb64;
  int NB5 = 1024; if (NB5 > nb64) NB5 = nb64;
  if (NB4 < 1) NB4 = 1; if (NB5 < 1) NB5 = 1;
  int GST = 512;  if (GST > nb) GST = nb; if (GST < 1) GST = 1;

  k_wprep<<<48, 256, 0, stream>>>(Wc4, W2d4, W3d4, Wat4, Wc5, wbf);
  k_stage1<<<nb, 256, 0, stream>>>(P, F1, Wc1, Bc1, W2d1, B2d1, W3d1, B3d1, Wat1, Bat1,
                                   u1, N);
  k_stats<16><<<GST, 256, 0, stream>>>(u1, S1, Q1, ncopy, N);
  k_stage<16><<<nb, 256, 0, stream>>>(u1, S1, Q1, G1, BE1, Wc2, Bc2, F2,
                                      W2d2, B2d2, W3d2, B3d2, Wat2, Bat2,
                                      u2, ncopy, invN, N);
  k_stats<32><<<GST, 256, 0, stream>>>(u2, S2, Q2, ncopy, N);
  k_stage<32><<<nb, 256, 0, stream>>>(u2, S2, Q2, G2, BE2, Wc3, Bc3, F3,
                                      W2d3, B2d3, W3d3, B3d3, Wat3, Bat3,
                                      u3, ncopy, invN, N);
  k_stats<64><<<GST, 256, 0, stream>>>(u3, S3, Q3, ncopy, N);
  k_pf<<<nb64, 256, 0, stream>>>(u3, S3, Q3, G3, BE3, out, ncopy, invN, N);
  k_stage4_mfma<<<NB4, 256, 0, stream>>>(u3, S3, Q3, G3, BE3, F4, wbf,
                                         Bc4, B2d4, B3d4, Bat4,
                                         u4, S4, Q4, ncopy, invN, N);
  k_stage5_mfma<<<NB5, 256, 0, stream>>>(u4, S4, Q4, G4, BE4, wbf + 16384, Bc5,
                                         S5, Q5, MX, MN, ncopy, invN, N);
  dim3 gfill((N / 8 + 255) / 256, 256, 1);
  k_fill<<<gfill, 256, 0, stream>>>(S5, Q5, MX, MN, G5, BE5, out, ncopy, invN, N);
}

// Round 5
// 1200.415 us; speedup vs baseline: 1.1814x; 1.1814x over previous
//
#include <hip/hip_runtime.h>

#define EPSV 1e-5f
#define STS 1536  // floats per stats copy (replicated accumulators)

typedef short bf16x8 __attribute__((ext_vector_type(8)));
typedef _Float16 f16x8 __attribute__((ext_vector_type(8)));
typedef float f32x4  __attribute__((ext_vector_type(4)));
#define MFMA_B16(a,b,c) __builtin_amdgcn_mfma_f32_16x16x32_bf16(a,b,c,0,0,0)
#define MFMA_F16(a,b,c) __builtin_amdgcn_mfma_f32_16x16x32_f16(a,b,c,0,0,0)

__device__ __forceinline__ unsigned short f2bf(float x){
  unsigned u = __float_as_uint(x);
  return (unsigned short)((u + 0x7fffu + ((u >> 16) & 1u)) >> 16);
}
__device__ __forceinline__ float bf2f(unsigned short h){ return __uint_as_float((unsigned)h << 16); }
__device__ __forceinline__ unsigned short f2h(float x){
  union { _Float16 h; unsigned short u; } cv; cv.h = (_Float16)x; return cv.u;
}
__device__ __forceinline__ float h2f(unsigned short u){
  union { _Float16 h; unsigned short u; } cv; cv.u = u; return (float)cv.h;
}

__device__ __forceinline__ float wredsum(float v){
  #pragma unroll
  for (int o = 32; o > 0; o >>= 1) v += __shfl_xor(v, o, 64);
  return v;
}
__device__ __forceinline__ float fsig(float x){ return 1.0f / (1.0f + __expf(-x)); }
__device__ __forceinline__ float ftanh(float x){ return 1.0f - 2.0f / (__expf(2.0f * x) + 1.0f); }

// ---------------- Weight prep A: fp32 -> bf16 (stage4/5 weights) into d_ws at ushort idx 0.
// [0,4096) Wc4; [4096,8192) W2d4; [8192,12288) W3d4; [12288,16384) Wat4; [16384,49152) W5
__global__ __launch_bounds__(256) void k_wprep(
    const float* __restrict__ wc4, const float* __restrict__ w2d4,
    const float* __restrict__ w3d4, const float* __restrict__ wat4,
    const float* __restrict__ w5, unsigned short* __restrict__ wbf)
{
  int i = (blockIdx.x * 256 + threadIdx.x) * 4;
  const float* src; int base;
  if      (i < 4096){  src = wc4;  base = 0; }
  else if (i < 8192){  src = w2d4; base = 4096; }
  else if (i < 12288){ src = w3d4; base = 8192; }
  else if (i < 16384){ src = wat4; base = 12288; }
  else              {  src = w5;   base = 16384; }
  float4 v = *(const float4*)(src + (i - base));
  ushort4 o;
  o.x = f2bf(v.x); o.y = f2bf(v.y); o.z = f2bf(v.z); o.w = f2bf(v.w);
  *(ushort4*)(wbf + i) = o;
}

// ---------------- Weight prep B: f16 matrices for stage2 (K-padded to 32) and stage3.
// at ushort idx 49152: wc2pad[16][32], w2d2pad[16][32] (f in upper K half), w3d2pad, wat2pad (512 each)
// at ushort idx 51200: wc3[32][32], w2d3, w3d3, wat3 (1024 each)
__global__ __launch_bounds__(256) void k_wprep2(
    const float* __restrict__ wc2, const float* __restrict__ w2d2,
    const float* __restrict__ w3d2, const float* __restrict__ wat2,
    const float* __restrict__ wc3, const float* __restrict__ w2d3,
    const float* __restrict__ w3d3, const float* __restrict__ wat3,
    unsigned short* __restrict__ wbf)
{
  const int t = threadIdx.x;
  for (int e = t; e < 2048; e += 256){
    int mat = e >> 9, idx = e & 511, m = idx >> 5, k = idx & 31;
    float v;
    if (mat == 1) v = (k >= 16) ? w2d2[m*16 + (k-16)] : 0.f;
    else {
      const float* w = (mat == 0) ? wc2 : (mat == 2) ? w3d2 : wat2;
      v = (k < 16) ? w[m*16 + k] : 0.f;
    }
    wbf[49152 + e] = f2h(v);
  }
  for (int e = t; e < 4096; e += 256){
    int mat = e >> 10, idx = e & 1023;
    const float* w = (mat == 0) ? wc3 : (mat == 1) ? w2d3 : (mat == 2) ? w3d3 : wat3;
    wbf[51200 + e] = f2h(w[idx]);
  }
}

// ---------------- Stage 1: points -> lin1(6->8)+relu -> fuse(C=8) -> u1 [N,16] fp32 + fused stats.
__global__ __launch_bounds__(256) void k_stage1(
    const float* __restrict__ pts, const float* __restrict__ f2d,
    const float* __restrict__ Wc, const float* __restrict__ bc,
    const float* __restrict__ W2d, const float* __restrict__ b2d,
    const float* __restrict__ W3d, const float* __restrict__ b3d,
    const float* __restrict__ Watt, const float* __restrict__ batt,
    float* __restrict__ uout, float* __restrict__ gS, float* __restrict__ gQ,
    int ncopy, int N)
{
  const int tid = threadIdx.x;
  __shared__ float sW1[48], s2d[64], s3d[64], sat[64];
  __shared__ float sS[16], sQ[16];
  if (tid < 48)                 sW1[tid]       = Wc[tid];
  if (tid >= 64  && tid < 128)  s2d[tid - 64]  = W2d[tid - 64];
  if (tid >= 128 && tid < 192)  s3d[tid - 128] = W3d[tid - 128];
  if (tid >= 192)               sat[tid - 192] = Watt[tid - 192];
  if (tid < 16){ sS[tid] = 0.f; sQ[tid] = 0.f; }
  __syncthreads();

  float as[8], aq[8], as2[8], aq2[8];
  #pragma unroll
  for (int i = 0; i < 8; i++){ as[i]=0.f; aq[i]=0.f; as2[i]=0.f; aq2[i]=0.f; }

  for (int n0 = blockIdx.x * 256; n0 < N; n0 += gridDim.x * 256){
    const int n = n0 + tid;
    const bool act = n < N;
    const size_t nc = act ? (size_t)n : 0;

    const float* p = pts + nc * 10;
    float xin[6];
    xin[0]=p[0]; xin[1]=p[1]; xin[2]=p[2]; xin[3]=p[7]; xin[4]=p[8]; xin[5]=p[9];
    float x1[8];
    #pragma unroll
    for (int i = 0; i < 8; i++){
      float a = bc[i];
      #pragma unroll
      for (int j = 0; j < 6; j++) a = fmaf(sW1[i*6+j], xin[j], a);
      x1[i] = fmaxf(a, 0.f);
    }
    float f[8];
    { const float4* fp4 = (const float4*)(f2d + nc * 8);
      float4 t0 = fp4[0], t1 = fp4[1];
      f[0]=t0.x; f[1]=t0.y; f[2]=t0.z; f[3]=t0.w;
      f[4]=t1.x; f[5]=t1.y; f[6]=t1.z; f[7]=t1.w; }
    float d2d[8];
    #pragma unroll
    for (int i = 0; i < 8; i++){
      const float4* w = (const float4*)(s2d + i*8);
      float4 w0 = w[0], w1 = w[1];
      float a = b2d[i];
      a = fmaf(w0.x, f[0], a); a = fmaf(w0.y, f[1], a);
      a = fmaf(w0.z, f[2], a); a = fmaf(w0.w, f[3], a);
      a = fmaf(w1.x, f[4], a); a = fmaf(w1.y, f[5], a);
      a = fmaf(w1.z, f[6], a); a = fmaf(w1.w, f[7], a);
      d2d[i] = a;
    }
    float mid[8];
    #pragma unroll
    for (int i = 0; i < 8; i++){
      const float4* w = (const float4*)(s3d + i*8);
      float4 w0 = w[0], w1 = w[1];
      float a = b3d[i] + d2d[i];
      a = fmaf(w0.x, x1[0], a); a = fmaf(w0.y, x1[1], a);
      a = fmaf(w0.z, x1[2], a); a = fmaf(w0.w, x1[3], a);
      a = fmaf(w1.x, x1[4], a); a = fmaf(w1.y, x1[5], a);
      a = fmaf(w1.z, x1[6], a); a = fmaf(w1.w, x1[7], a);
      mid[i] = ftanh(a);
    }
    float r[8];
    #pragma unroll
    for (int i = 0; i < 8; i++){
      const float4* w = (const float4*)(sat + i*8);
      float4 w0 = w[0], w1 = w[1];
      float a = batt[i];
      a = fmaf(w0.x, mid[0], a); a = fmaf(w0.y, mid[1], a);
      a = fmaf(w0.z, mid[2], a); a = fmaf(w0.w, mid[3], a);
      a = fmaf(w1.x, mid[4], a); a = fmaf(w1.y, mid[5], a);
      a = fmaf(w1.z, mid[6], a); a = fmaf(w1.w, mid[7], a);
      r[i] = fsig(a) * d2d[i];
    }
    if (act){
      float* urow = uout + nc * 16;
      *(float4*)(urow + 0)  = make_float4(x1[0], x1[1], x1[2], x1[3]);
      *(float4*)(urow + 4)  = make_float4(x1[4], x1[5], x1[6], x1[7]);
      *(float4*)(urow + 8)  = make_float4(r[0], r[1], r[2], r[3]);
      *(float4*)(urow + 12) = make_float4(r[4], r[5], r[6], r[7]);
    }
    #pragma unroll
    for (int i = 0; i < 8; i++){
      float v = act ? x1[i] : 0.f;
      as[i] += v; aq[i] += v * v;
      float v2 = act ? r[i] : 0.f;
      as2[i] += v2; aq2[i] += v2 * v2;
    }
  }
  #pragma unroll
  for (int i = 0; i < 8; i++){
    float s = wredsum(as[i]), qv = wredsum(aq[i]);
    float s2 = wredsum(as2[i]), q2 = wredsum(aq2[i]);
    if ((tid & 63) == 0){
      atomicAdd(&sS[i], s);     atomicAdd(&sQ[i], qv);
      atomicAdd(&sS[8+i], s2);  atomicAdd(&sQ[8+i], q2);
    }
  }
  __syncthreads();
  if (tid < 16){
    const int co = (blockIdx.x & (ncopy - 1)) * STS;
    atomicAdd(&gS[co + tid], sS[tid]); atomicAdd(&gQ[co + tid], sQ[tid]);
  }
}

// ---------------- Stage 2 MFMA (C=16, K padded to 32 with [act|f] packing):
// BN1(u1) -> relu(Wc2)+fuse2 -> u2 [N,32] f16 + fused stats.
__global__ __launch_bounds__(256) void k_stage2_mfma(
    const float* __restrict__ u1, const float* __restrict__ pS, const float* __restrict__ pQ,
    const float* __restrict__ gam, const float* __restrict__ bet,
    const float* __restrict__ f2d,
    const unsigned short* __restrict__ wh,   // wc2pad@0, w2d2pad@512, w3d2pad@1024, wat2pad@1536
    const float* __restrict__ bc, const float* __restrict__ b2d,
    const float* __restrict__ b3d, const float* __restrict__ batt,
    unsigned short* __restrict__ u2o, float* __restrict__ gS, float* __restrict__ gQ,
    int ncopy, float invN, int N)
{
  const int tid = threadIdx.x;
  __shared__ float sA[16], sB[16];
  __shared__ unsigned short yb[64*24], fb[64*24], xb[64*24], mb[64*24];
  __shared__ float sS[32], sQ[32];
  if (tid < 16){
    float s = 0.f, qv = 0.f;
    for (int c = 0; c < ncopy; c++){ s += pS[c*STS + tid]; qv += pQ[c*STS + tid]; }
    float m = s * invN;
    float v = qv * invN - m * m;
    float a = gam[tid] * rsqrtf(v + EPSV);
    sA[tid] = a; sB[tid] = fmaf(-a, m, bet[tid]);
  }
  if (tid < 32){ sS[tid] = 0.f; sQ[tid] = 0.f; }
  __syncthreads();

  const int w = tid >> 6;
  const int lane = tid & 63;
  const int cN = lane & 15;
  const int q = lane >> 4;
  const int brow = w*16 + cN;

  f16x8 aWc = *(const f16x8*)(wh + 0    + cN*32 + q*8);
  f16x8 aW2 = *(const f16x8*)(wh + 512  + cN*32 + q*8);
  f16x8 aW3 = *(const f16x8*)(wh + 1024 + cN*32 + q*8);
  f16x8 aWa = *(const f16x8*)(wh + 1536 + cN*32 + q*8);
  f32x4 bbc = *(const f32x4*)(bc   + q*4);
  f32x4 bb2 = *(const f32x4*)(b2d  + q*4);
  f32x4 bb3 = *(const f32x4*)(b3d  + q*4);
  f32x4 bba = *(const f32x4*)(batt + q*4);

  // B-frag: K=32 rows are logically [act(16) | f(16)]; q<2 reads act buffer, q>=2 reads fb.
  #define BF2(buf) (*(const f16x8*)(((q < 2) ? (buf) : fb) + brow*24 + (q & 1)*8))

  f32x4 ssx = {0,0,0,0}, qqx = {0,0,0,0};
  f32x4 ssr = {0,0,0,0}, qqr = {0,0,0,0};

  for (int pt0 = blockIdx.x * 64; pt0 < N; pt0 += gridDim.x * 64){
    { // staging: y = BN1(u1) f16 -> yb; f2 -> fb
      const int pt = tid >> 2, seg = tid & 3;
      const int gpt = pt0 + pt;
      const bool v = gpt < N;
      float4 t  = *(const float4*)(u1  + (size_t)(v ? gpt : 0) * 16 + seg*4);
      float4 ff = *(const float4*)(f2d + (size_t)(v ? gpt : 0) * 16 + seg*4);
      const float* a = sA + seg*4;
      const float* b = sB + seg*4;
      float y0 = v ? fmaf(a[0], t.x, b[0]) : 0.f;
      float y1 = v ? fmaf(a[1], t.y, b[1]) : 0.f;
      float y2 = v ? fmaf(a[2], t.z, b[2]) : 0.f;
      float y3 = v ? fmaf(a[3], t.w, b[3]) : 0.f;
      uint2 yw, fw;
      yw.x = (unsigned)f2h(y0) | ((unsigned)f2h(y1) << 16);
      yw.y = (unsigned)f2h(y2) | ((unsigned)f2h(y3) << 16);
      fw.x = (unsigned)f2h(v ? ff.x : 0.f) | ((unsigned)f2h(v ? ff.y : 0.f) << 16);
      fw.y = (unsigned)f2h(v ? ff.z : 0.f) | ((unsigned)f2h(v ? ff.w : 0.f) << 16);
      *(uint2*)(yb + pt*24 + seg*4) = yw;
      *(uint2*)(fb + pt*24 + seg*4) = fw;
    }
    __syncthreads();

    const bool vc = (pt0 + brow) < N;
    // G1: x = relu(Wc y + bc); d2d = W2d f + b2d  (shared B-frag [y|f])
    f16x8 Bv = BF2(yb);
    f32x4 accx = MFMA_F16(aWc, Bv, bbc);
    f32x4 accd = MFMA_F16(aW2, Bv, bb2);
    f32x4 xv;
    #pragma unroll
    for (int r = 0; r < 4; r++){
      float z = fmaxf(accx[r], 0.f);
      xv[r] = z;
      float zm = vc ? z : 0.f;
      ssx[r] += zm; qqx[r] += zm * zm;
    }
    uint2 pk;
    pk.x = (unsigned)f2h(xv[0]) | ((unsigned)f2h(xv[1]) << 16);
    pk.y = (unsigned)f2h(xv[2]) | ((unsigned)f2h(xv[3]) << 16);
    *(uint2*)(xb + brow*24 + q*4) = pk;
    if (vc) *(uint2*)(u2o + (size_t)(pt0 + brow) * 32 + q*4) = pk;
    __syncthreads();

    // G2: mid = tanh(W3d x + b3d + d2d)
    f32x4 accm = MFMA_F16(aW3, BF2(xb), bb3 + accd);
    #pragma unroll
    for (int r = 0; r < 4; r++) accm[r] = ftanh(accm[r]);
    pk.x = (unsigned)f2h(accm[0]) | ((unsigned)f2h(accm[1]) << 16);
    pk.y = (unsigned)f2h(accm[2]) | ((unsigned)f2h(accm[3]) << 16);
    *(uint2*)(mb + brow*24 + q*4) = pk;
    __syncthreads();

    // G3: r = sigmoid(Watt mid + batt) * d2d
    f32x4 acca = MFMA_F16(aWa, BF2(mb), bba);
    f32x4 rv;
    #pragma unroll
    for (int r = 0; r < 4; r++){
      float rr = fsig(acca[r]) * accd[r];
      rv[r] = rr;
      float zm = vc ? rr : 0.f;
      ssr[r] += zm; qqr[r] += zm * zm;
    }
    if (vc){
      uint2 rk;
      rk.x = (unsigned)f2h(rv[0]) | ((unsigned)f2h(rv[1]) << 16);
      rk.y = (unsigned)f2h(rv[2]) | ((unsigned)f2h(rv[3]) << 16);
      *(uint2*)(u2o + (size_t)(pt0 + brow) * 32 + 16 + q*4) = rk;
    }
    __syncthreads();  // G3 reads fb; next staging overwrites fb
  }
  #undef BF2

  // stats: reduce over cN lanes, LDS-combine across waves, one global atomic set
  #pragma unroll
  for (int r = 0; r < 4; r++){
    float s = ssx[r], qq = qqx[r], s2 = ssr[r], q2 = qqr[r];
    #pragma unroll
    for (int m = 1; m < 16; m <<= 1){
      s  += __shfl_xor(s,  m, 64); qq += __shfl_xor(qq, m, 64);
      s2 += __shfl_xor(s2, m, 64); q2 += __shfl_xor(q2, m, 64);
    }
    if (cN == 0){
      int ch = q*4 + r;
      atomicAdd(&sS[ch], s);       atomicAdd(&sQ[ch], qq);
      atomicAdd(&sS[16 + ch], s2); atomicAdd(&sQ[16 + ch], q2);
    }
  }
  __syncthreads();
  if (tid < 32){
    const int co = (blockIdx.x & (ncopy - 1)) * STS;
    atomicAdd(&gS[co + tid], sS[tid]); atomicAdd(&gQ[co + tid], sQ[tid]);
  }
}

// ---------------- Stage 3 MFMA (C=32, K=32 native): BN2(u2 f16) -> relu(Wc3)+fuse3 -> u3 [N,64] f16 + stats
__global__ __launch_bounds__(256) void k_stage3_mfma(
    const unsigned short* __restrict__ u2, const float* __restrict__ pS, const float* __restrict__ pQ,
    const float* __restrict__ gam, const float* __restrict__ bet,
    const float* __restrict__ f2d,
    const unsigned short* __restrict__ wh,   // wc3@0, w2d3@1024, w3d3@2048, wat3@3072
    const float* __restrict__ bc, const float* __restrict__ b2d,
    const float* __restrict__ b3d, const float* __restrict__ batt,
    unsigned short* __restrict__ u3o, float* __restrict__ gS, float* __restrict__ gQ,
    int ncopy, float invN, int N)
{
  const int tid = threadIdx.x;
  __shared__ float sA[32], sB[32];
  __shared__ unsigned short yb[64*40], fb[64*40], xb[64*40], mb[64*40];
  __shared__ float sS[64], sQ[64];
  if (tid < 32){
    float s = 0.f, qv = 0.f;
    for (int c = 0; c < ncopy; c++){ s += pS[c*STS + tid]; qv += pQ[c*STS + tid]; }
    float m = s * invN;
    float v = qv * invN - m * m;
    float a = gam[tid] * rsqrtf(v + EPSV);
    sA[tid] = a; sB[tid] = fmaf(-a, m, bet[tid]);
  }
  if (tid < 64){ sS[tid] = 0.f; sQ[tid] = 0.f; }
  __syncthreads();

  const int w = tid >> 6;
  const int lane = tid & 63;
  const int cN = lane & 15;
  const int q = lane >> 4;
  const int brow = w*16 + cN;

  f16x8 aWc[2], aW2[2], aW3[2], aWa[2];
  f32x4 bbc[2], bb2[2], bb3[2], bba[2];
  #pragma unroll
  for (int mg = 0; mg < 2; mg++){
    int off = (mg*16 + cN)*32 + q*8;
    aWc[mg] = *(const f16x8*)(wh + 0    + off);
    aW2[mg] = *(const f16x8*)(wh + 1024 + off);
    aW3[mg] = *(const f16x8*)(wh + 2048 + off);
    aWa[mg] = *(const f16x8*)(wh + 3072 + off);
    bbc[mg] = *(const f32x4*)(bc   + mg*16 + q*4);
    bb2[mg] = *(const f32x4*)(b2d  + mg*16 + q*4);
    bb3[mg] = *(const f32x4*)(b3d  + mg*16 + q*4);
    bba[mg] = *(const f32x4*)(batt + mg*16 + q*4);
  }

  #define BF3(buf) (*(const f16x8*)((buf) + brow*40 + q*8))

  f32x4 ssx[2], qqx[2], ssr[2], qqr[2];
  #pragma unroll
  for (int mg = 0; mg < 2; mg++){
    ssx[mg] = (f32x4){0,0,0,0}; qqx[mg] = (f32x4){0,0,0,0};
    ssr[mg] = (f32x4){0,0,0,0}; qqr[mg] = (f32x4){0,0,0,0};
  }

  for (int pt0 = blockIdx.x * 64; pt0 < N; pt0 += gridDim.x * 64){
    { // staging: y = BN2(u2 f16) -> yb f16; f3 fp32 -> fb f16
      const int pt = tid >> 2, seg = tid & 3;
      const int gpt = pt0 + pt;
      const bool v = gpt < N;
      uint4 t = *(const uint4*)(u2 + (size_t)(v ? gpt : 0) * 32 + seg*8);
      unsigned hw[4] = {t.x, t.y, t.z, t.w};
      unsigned ow[4];
      #pragma unroll
      for (int k = 0; k < 4; k++){
        int c0 = seg*8 + 2*k;
        float v0 = v ? fmaf(sA[c0],   h2f((unsigned short)(hw[k] & 0xffff)), sB[c0])   : 0.f;
        float v1 = v ? fmaf(sA[c0+1], h2f((unsigned short)(hw[k] >> 16)),    sB[c0+1]) : 0.f;
        ow[k] = (unsigned)f2h(v0) | ((unsigned)f2h(v1) << 16);
      }
      uint4 o; o.x = ow[0]; o.y = ow[1]; o.z = ow[2]; o.w = ow[3];
      *(uint4*)(yb + pt*40 + seg*8) = o;

      float4 f0 = *(const float4*)(f2d + (size_t)(v ? gpt : 0) * 32 + seg*8);
      float4 f1 = *(const float4*)(f2d + (size_t)(v ? gpt : 0) * 32 + seg*8 + 4);
      uint4 fo;
      fo.x = (unsigned)f2h(v ? f0.x : 0.f) | ((unsigned)f2h(v ? f0.y : 0.f) << 16);
      fo.y = (unsigned)f2h(v ? f0.z : 0.f) | ((unsigned)f2h(v ? f0.w : 0.f) << 16);
      fo.z = (unsigned)f2h(v ? f1.x : 0.f) | ((unsigned)f2h(v ? f1.y : 0.f) << 16);
      fo.w = (unsigned)f2h(v ? f1.z : 0.f) | ((unsigned)f2h(v ? f1.w : 0.f) << 16);
      *(uint4*)(fb + pt*40 + seg*8) = fo;
    }
    __syncthreads();

    const bool vc = (pt0 + brow) < N;
    // G1: x = relu(Wc3 y + bc); d2d = W2d3 f + b2d
    f16x8 By = BF3(yb);
    f16x8 Bf = BF3(fb);
    f32x4 accd[2];
    #pragma unroll
    for (int mg = 0; mg < 2; mg++){
      f32x4 accx = MFMA_F16(aWc[mg], By, bbc[mg]);
      accd[mg]   = MFMA_F16(aW2[mg], Bf, bb2[mg]);
      f32x4 xv;
      #pragma unroll
      for (int r = 0; r < 4; r++){
        float z = fmaxf(accx[r], 0.f);
        xv[r] = z;
        float zm = vc ? z : 0.f;
        ssx[mg][r] += zm; qqx[mg][r] += zm * zm;
      }
      uint2 pk;
      pk.x = (unsigned)f2h(xv[0]) | ((unsigned)f2h(xv[1]) << 16);
      pk.y = (unsigned)f2h(xv[2]) | ((unsigned)f2h(xv[3]) << 16);
      *(uint2*)(xb + brow*40 + mg*16 + q*4) = pk;
      if (vc) *(uint2*)(u3o + (size_t)(pt0 + brow) * 64 + mg*16 + q*4) = pk;
    }
    __syncthreads();

    // G2: mid = tanh(W3d3 x + b3d + d2d)
    f16x8 Bx = BF3(xb);
    #pragma unroll
    for (int mg = 0; mg < 2; mg++){
      f32x4 accm = MFMA_F16(aW3[mg], Bx, bb3[mg] + accd[mg]);
      #pragma unroll
      for (int r = 0; r < 4; r++) accm[r] = ftanh(accm[r]);
      uint2 pk;
      pk.x = (unsigned)f2h(accm[0]) | ((unsigned)f2h(accm[1]) << 16);
      pk.y = (unsigned)f2h(accm[2]) | ((unsigned)f2h(accm[3]) << 16);
      *(uint2*)(mb + brow*40 + mg*16 + q*4) = pk;
    }
    __syncthreads();

    // G3: r = sigmoid(Wat3 mid + batt) * d2d -> u3[.,32..63]
    f16x8 Bm = BF3(mb);
    #pragma unroll
    for (int mg = 0; mg < 2; mg++){
      f32x4 acca = MFMA_F16(aWa[mg], Bm, bba[mg]);
      f32x4 rv;
      #pragma unroll
      for (int r = 0; r < 4; r++){
        float rr = fsig(acca[r]) * accd[mg][r];
        rv[r] = rr;
        float zm = vc ? rr : 0.f;
        ssr[mg][r] += zm; qqr[mg][r] += zm * zm;
      }
      if (vc){
        uint2 rk;
        rk.x = (unsigned)f2h(rv[0]) | ((unsigned)f2h(rv[1]) << 16);
        rk.y = (unsigned)f2h(rv[2]) | ((unsigned)f2h(rv[3]) << 16);
        *(uint2*)(u3o + (size_t)(pt0 + brow) * 64 + 32 + mg*16 + q*4) = rk;
      }
    }
    // no barrier needed: next staging writes yb/fb; their last reads (G1) are 2 barriers back.
  }
  #undef BF3

  #pragma unroll
  for (int mg = 0; mg < 2; mg++){
    #pragma unroll
    for (int r = 0; r < 4; r++){
      float s = ssx[mg][r], qq = qqx[mg][r], s2 = ssr[mg][r], q2 = qqr[mg][r];
      #pragma unroll
      for (int m = 1; m < 16; m <<= 1){
        s  += __shfl_xor(s,  m, 64); qq += __shfl_xor(qq, m, 64);
        s2 += __shfl_xor(s2, m, 64); q2 += __shfl_xor(q2, m, 64);
      }
      if (cN == 0){
        int ch = mg*16 + q*4 + r;
        atomicAdd(&sS[ch], s);       atomicAdd(&sQ[ch], qq);
        atomicAdd(&sS[32 + ch], s2); atomicAdd(&sQ[32 + ch], q2);
      }
    }
  }
  __syncthreads();
  if (tid < 64){
    const int co = (blockIdx.x & (ncopy - 1)) * STS;
    atomicAdd(&gS[co + tid], sS[tid]); atomicAdd(&gQ[co + tid], sQ[tid]);
  }
}

// ---------------- Stage 4 MFMA (C=64): u3 now f16. Persistent, register stats.
__global__ __launch_bounds__(256) void k_stage4_mfma(
    const unsigned short* __restrict__ u3, const float* __restrict__ pS, const float* __restrict__ pQ,
    const float* __restrict__ gam, const float* __restrict__ bet,
    const float* __restrict__ f2d,
    const unsigned short* __restrict__ wbf,   // wc4@0, w2d4@4096, w3d4@8192, wat4@12288
    const float* __restrict__ bc, const float* __restrict__ b2d,
    const float* __restrict__ b3d, const float* __restrict__ batt,
    unsigned short* __restrict__ u4o, float* __restrict__ gS, float* __restrict__ gQ,
    int ncopy, float invN, int N)
{
  const int tid = threadIdx.x;
  __shared__ float sA[64], sB[64];
  __shared__ unsigned short yb[64*72], fb[64*72], xb[64*72], mb[64*72], rb[64*72];

  if (tid < 64){
    float s = 0.f, qv = 0.f;
    for (int c = 0; c < ncopy; c++){ s += pS[c*STS + tid]; qv += pQ[c*STS + tid]; }
    float m = s * invN;
    float v = qv * invN - m * m;
    float a = gam[tid] * rsqrtf(v + EPSV);
    sA[tid] = a; sB[tid] = fmaf(-a, m, bet[tid]);
  }
  __syncthreads();

  const int w = tid >> 6;
  const int lane = tid & 63;
  const int cN = lane & 15;
  const int q = lane >> 4;

  bf16x8 aWc[2], aW2[2], aW3[2], aWa[2];
  #pragma unroll
  for (int kc = 0; kc < 2; kc++){
    size_t off = (size_t)(w*16 + cN) * 64 + kc*32 + q*8;
    aWc[kc] = *(const bf16x8*)(wbf + off);
    aW2[kc] = *(const bf16x8*)(wbf + 4096 + off);
    aW3[kc] = *(const bf16x8*)(wbf + 8192 + off);
    aWa[kc] = *(const bf16x8*)(wbf + 12288 + off);
  }
  f32x4 bbc = *(const f32x4*)(bc   + w*16 + q*4);
  f32x4 bb2 = *(const f32x4*)(b2d  + w*16 + q*4);
  f32x4 bb3 = *(const f32x4*)(b3d  + w*16 + q*4);
  f32x4 bba = *(const f32x4*)(batt + w*16 + q*4);

  #define BFRAG(buf, p, kc) (*(const bf16x8*)((buf) + ((p)*16 + cN)*72 + (kc)*32 + q*8))

  f32x4 ssx = {0,0,0,0}, qqx = {0,0,0,0};
  f32x4 ssr = {0,0,0,0}, qqr = {0,0,0,0};

  for (int pt0 = blockIdx.x * 64; pt0 < N; pt0 += gridDim.x * 64){
    { // staging: y = BN3(u3 f16) bf16 -> yb; f4 -> fb
      const int pt = tid >> 2;
      const int c16 = (tid & 3) << 4;
      const int gpt = pt0 + pt;
      const bool v = gpt < N;
      const unsigned short* ur = u3 + (size_t)(v ? gpt : 0) * 64 + c16;
      const float4* fr = (const float4*)(f2d + (size_t)(v ? gpt : 0) * 64 + c16);
      uint4 t0 = *(const uint4*)(ur);
      uint4 t1 = *(const uint4*)(ur + 8);
      unsigned hw[8] = {t0.x, t0.y, t0.z, t0.w, t1.x, t1.y, t1.z, t1.w};
      #pragma unroll
      for (int i = 0; i < 4; i++){
        float u0 = h2f((unsigned short)(hw[2*i] & 0xffff));
        float u1v = h2f((unsigned short)(hw[2*i] >> 16));
        float u2v = h2f((unsigned short)(hw[2*i+1] & 0xffff));
        float u3v = h2f((unsigned short)(hw[2*i+1] >> 16));
        float4 ff = fr[i];
        float4 a = *(const float4*)(sA + c16 + 4*i);
        float4 b = *(const float4*)(sB + c16 + 4*i);
        float y0 = v ? fmaf(a.x, u0, b.x) : 0.f;
        float y1 = v ? fmaf(a.y, u1v, b.y) : 0.f;
        float y2 = v ? fmaf(a.z, u2v, b.z) : 0.f;
        float y3 = v ? fmaf(a.w, u3v, b.w) : 0.f;
        uint2 yw, fw;
        yw.x = (unsigned)f2bf(y0) | ((unsigned)f2bf(y1) << 16);
        yw.y = (unsigned)f2bf(y2) | ((unsigned)f2bf(y3) << 16);
        fw.x = (unsigned)f2bf(v ? ff.x : 0.f) | ((unsigned)f2bf(v ? ff.y : 0.f) << 16);
        fw.y = (unsigned)f2bf(v ? ff.z : 0.f) | ((unsigned)f2bf(v ? ff.w : 0.f) << 16);
        *(uint2*)(yb + pt*72 + c16 + 4*i) = yw;
        *(uint2*)(fb + pt*72 + c16 + 4*i) = fw;
      }
    }
    __syncthreads();

    f32x4 d2d[4];
    #pragma unroll
    for (int p = 0; p < 4; p++){
      f32x4 acc = bb2;
      acc = MFMA_B16(aW2[0], BFRAG(fb, p, 0), acc);
      acc = MFMA_B16(aW2[1], BFRAG(fb, p, 1), acc);
      d2d[p] = acc;
    }
    #pragma unroll
    for (int p = 0; p < 4; p++){
      f32x4 acc = bbc;
      acc = MFMA_B16(aWc[0], BFRAG(yb, p, 0), acc);
      acc = MFMA_B16(aWc[1], BFRAG(yb, p, 1), acc);
      const bool vc = (pt0 + p*16 + cN) < N;
      #pragma unroll
      for (int r = 0; r < 4; r++){
        float z = fmaxf(acc[r], 0.f);
        acc[r] = z;
        float zm = vc ? z : 0.f;
        ssx[r] += zm; qqx[r] += zm * zm;
      }
      uint2 pk;
      pk.x = (unsigned)f2bf(acc[0]) | ((unsigned)f2bf(acc[1]) << 16);
      pk.y = (unsigned)f2bf(acc[2]) | ((unsigned)f2bf(acc[3]) << 16);
      *(uint2*)(xb + (p*16 + cN)*72 + w*16 + q*4) = pk;
    }
    __syncthreads();
    #pragma unroll
    for (int p = 0; p < 4; p++){
      f32x4 acc = bb3 + d2d[p];
      acc = MFMA_B16(aW3[0], BFRAG(xb, p, 0), acc);
      acc = MFMA_B16(aW3[1], BFRAG(xb, p, 1), acc);
      #pragma unroll
      for (int r = 0; r < 4; r++) acc[r] = ftanh(acc[r]);
      uint2 pk;
      pk.x = (unsigned)f2bf(acc[0]) | ((unsigned)f2bf(acc[1]) << 16);
      pk.y = (unsigned)f2bf(acc[2]) | ((unsigned)f2bf(acc[3]) << 16);
      *(uint2*)(mb + (p*16 + cN)*72 + w*16 + q*4) = pk;
    }
    __syncthreads();
    #pragma unroll
    for (int p = 0; p < 4; p++){
      f32x4 acc = bba;
      acc = MFMA_B16(aWa[0], BFRAG(mb, p, 0), acc);
      acc = MFMA_B16(aWa[1], BFRAG(mb, p, 1), acc);
      const bool vc = (pt0 + p*16 + cN) < N;
      #pragma unroll
      for (int r = 0; r < 4; r++){
        float rr = fsig(acc[r]) * d2d[p][r];
        acc[r] = rr;
        float zm = vc ? rr : 0.f;
        ssr[r] += zm; qqr[r] += zm * zm;
      }
      uint2 pk;
      pk.x = (unsigned)f2bf(acc[0]) | ((unsigned)f2bf(acc[1]) << 16);
      pk.y = (unsigned)f2bf(acc[2]) | ((unsigned)f2bf(acc[3]) << 16);
      *(uint2*)(rb + (p*16 + cN)*72 + w*16 + q*4) = pk;
    }
    __syncthreads();
    {
      const int pt = tid >> 2;
      const int quarter = tid & 3;
      const int gpt = pt0 + pt;
      if (gpt < N){
        const unsigned short* src = (quarter < 2 ? xb : rb) + pt*72 + (quarter & 1)*32;
        unsigned short* dst = u4o + (size_t)gpt * 128 + quarter*32;
        #pragma unroll
        for (int i = 0; i < 4; i++)
          *(uint4*)(dst + 8*i) = *(const uint4*)(src + 8*i);
      }
    }
  }

  const int co = (blockIdx.x & (ncopy - 1)) * STS;
  #pragma unroll
  for (int r = 0; r < 4; r++){
    float s = ssx[r], qq = qqx[r], s2 = ssr[r], q2 = qqr[r];
    #pragma unroll
    for (int m = 1; m < 16; m <<= 1){
      s  += __shfl_xor(s,  m, 64); qq += __shfl_xor(qq, m, 64);
      s2 += __shfl_xor(s2, m, 64); q2 += __shfl_xor(q2, m, 64);
    }
    if (cN == 0){
      int ch = w*16 + q*4 + r;
      atomicAdd(&gS[co + ch], s);       atomicAdd(&gQ[co + ch], qq);
      atomicAdd(&gS[co + 64 + ch], s2); atomicAdd(&gQ[co + 64 + ch], q2);
    }
  }
  #undef BFRAG
}

// ---------------- Stage 5 MFMA: unchanged (reads bf16 u4)
__global__ __launch_bounds__(256) void k_stage5_mfma(
    const unsigned short* __restrict__ u4, const float* __restrict__ pS, const float* __restrict__ pQ,
    const float* __restrict__ gam, const float* __restrict__ bet,
    const unsigned short* __restrict__ w5bf, const float* __restrict__ b5,
    float* __restrict__ gS, float* __restrict__ gQ,
    int* __restrict__ gMx, int* __restrict__ gMn,
    int ncopy, float invN, int N)
{
  const int tid = threadIdx.x;
  __shared__ float sA[128], sB[128];
  __shared__ unsigned short yb[64*136];

  if (tid < 128){
    float s = 0.f, qv = 0.f;
    for (int c = 0; c < ncopy; c++){ s += pS[c*STS + tid]; qv += pQ[c*STS + tid]; }
    float m = s * invN;
    float v = qv * invN - m * m;
    float a = gam[tid] * rsqrtf(v + EPSV);
    sA[tid] = a; sB[tid] = fmaf(-a, m, bet[tid]);
  }
  __syncthreads();

  const int w = tid >> 6;
  const int lane = tid & 63;
  const int cN = lane & 15;
  const int q = lane >> 4;

  bf16x8 aW[4][4];
  f32x4 bb[4];
  #pragma unroll
  for (int mg = 0; mg < 4; mg++){
    int m = (w*4 + mg)*16 + cN;
    #pragma unroll
    for (int kc = 0; kc < 4; kc++)
      aW[mg][kc] = *(const bf16x8*)(w5bf + (size_t)m*128 + kc*32 + q*8);
    bb[mg] = *(const f32x4*)(b5 + (w*4 + mg)*16 + q*4);
  }

  const float FINF = __int_as_float(0x7f800000);
  f32x4 s5[4], q5[4], mx5[4], mn5[4];
  #pragma unroll
  for (int mg = 0; mg < 4; mg++){
    s5[mg] = (f32x4){0,0,0,0}; q5[mg] = (f32x4){0,0,0,0};
    mx5[mg] = (f32x4){0,0,0,0};
    mn5[mg] = (f32x4){FINF, FINF, FINF, FINF};
  }

  for (int pt0 = blockIdx.x * 64; pt0 < N; pt0 += gridDim.x * 64){
    {
      const int pt = tid >> 2;
      const int t3 = tid & 3;
      const int c32 = t3 << 5;
      const int gpt = pt0 + pt;
      const bool v = gpt < N;
      const unsigned short* ur = u4 + (size_t)(v ? gpt : 0) * 128 + c32;
      #pragma unroll
      for (int ii = 0; ii < 4; ii++){
        const int i = (ii + t3) & 3;
        uint4 t = *(const uint4*)(ur + 8*i);
        const float* a = sA + c32 + 8*i;
        const float* b = sB + c32 + 8*i;
        unsigned tv[4] = {t.x, t.y, t.z, t.w};
        uint4 o;
        unsigned ov[4];
        #pragma unroll
        for (int k = 0; k < 4; k++){
          float v0 = v ? fmaf(a[2*k],   bf2f((unsigned short)(tv[k] & 0xffff)), b[2*k])   : 0.f;
          float v1 = v ? fmaf(a[2*k+1], bf2f((unsigned short)(tv[k] >> 16)),    b[2*k+1]) : 0.f;
          ov[k] = (unsigned)f2bf(v0) | ((unsigned)f2bf(v1) << 16);
        }
        o.x = ov[0]; o.y = ov[1]; o.z = ov[2]; o.w = ov[3];
        *(uint4*)(yb + pt*136 + c32 + 8*i) = o;
      }
    }
    __syncthreads();

    #pragma unroll
    for (int p = 0; p < 4; p++){
      bf16x8 B0 = *(const bf16x8*)(yb + (p*16 + cN)*136 + 0*32 + q*8);
      bf16x8 B1 = *(const bf16x8*)(yb + (p*16 + cN)*136 + 1*32 + q*8);
      bf16x8 B2 = *(const bf16x8*)(yb + (p*16 + cN)*136 + 2*32 + q*8);
      bf16x8 B3 = *(const bf16x8*)(yb + (p*16 + cN)*136 + 3*32 + q*8);
      const bool vc = (pt0 + p*16 + cN) < N;
      #pragma unroll
      for (int mg = 0; mg < 4; mg++){
        f32x4 acc = bb[mg];
        acc = MFMA_B16(aW[mg][0], B0, acc);
        acc = MFMA_B16(aW[mg][1], B1, acc);
        acc = MFMA_B16(aW[mg][2], B2, acc);
        acc = MFMA_B16(aW[mg][3], B3, acc);
        #pragma unroll
        for (int r = 0; r < 4; r++){
          float z = fmaxf(acc[r], 0.f);
          float zm = vc ? z : 0.f;
          s5[mg][r] += zm; q5[mg][r] += zm * zm;
          mx5[mg][r] = fmaxf(mx5[mg][r], zm);
          mn5[mg][r] = fminf(mn5[mg][r], vc ? z : FINF);
        }
      }
    }
    __syncthreads();
  }

  const int co = (blockIdx.x & (ncopy - 1)) * STS;
  #pragma unroll
  for (int mg = 0; mg < 4; mg++){
    #pragma unroll
    for (int r = 0; r < 4; r++){
      float s = s5[mg][r], qq = q5[mg][r], mx = mx5[mg][r], mn = mn5[mg][r];
      #pragma unroll
      for (int m = 1; m < 16; m <<= 1){
        s  += __shfl_xor(s,  m, 64); qq += __shfl_xor(qq, m, 64);
        mx = fmaxf(mx, __shfl_xor(mx, m, 64));
        mn = fminf(mn, __shfl_xor(mn, m, 64));
      }
      if (cN == 0){
        int ch = (w*4 + mg)*16 + q*4 + r;
        atomicAdd(&gS[co + ch], s); atomicAdd(&gQ[co + ch], qq);
        atomicMax(&gMx[co + ch], __float_as_int(mx));
        atomicMin(&gMn[co + ch], __float_as_int(mn));
      }
    }
  }
}

// ---------------- point_feature: out rows [256..320) = transpose(BN3(u3 f16)), fp32 out
__global__ __launch_bounds__(256) void k_pf(
    const unsigned short* __restrict__ u3, const float* __restrict__ pS, const float* __restrict__ pQ,
    const float* __restrict__ gam, const float* __restrict__ bet,
    float* __restrict__ out, int ncopy, float invN, int N)
{
  const int tid = threadIdx.x;
  const int n0 = blockIdx.x * 64;
  __shared__ float sA[64], sB[64];
  __shared__ float T[64][68];
  if (tid < 64){
    float s = 0.f, qv = 0.f;
    for (int c = 0; c < ncopy; c++){ s += pS[c*STS + tid]; qv += pQ[c*STS + tid]; }
    float m = s * invN;
    float v = qv * invN - m * m;
    float a = gam[tid] * rsqrtf(v + EPSV);
    sA[tid] = a; sB[tid] = fmaf(-a, m, bet[tid]);
  }
  __syncthreads();
  {
    const int r = tid >> 2;
    const int c16 = (tid & 3) << 4;
    const int gn = n0 + r;
    const bool v = gn < N;
    const unsigned short* ur = u3 + (size_t)(v ? gn : 0) * 64 + c16;
    uint4 t0 = *(const uint4*)(ur);
    uint4 t1 = *(const uint4*)(ur + 8);
    unsigned hw[8] = {t0.x, t0.y, t0.z, t0.w, t1.x, t1.y, t1.z, t1.w};
    #pragma unroll
    for (int i = 0; i < 4; i++){
      float u0 = h2f((unsigned short)(hw[2*i] & 0xffff));
      float u1v = h2f((unsigned short)(hw[2*i] >> 16));
      float u2v = h2f((unsigned short)(hw[2*i+1] & 0xffff));
      float u3v = h2f((unsigned short)(hw[2*i+1] >> 16));
      float4 a = *(const float4*)(sA + c16 + 4*i);
      float4 b = *(const float4*)(sB + c16 + 4*i);
      T[c16 + 4*i + 0][r] = v ? fmaf(a.x, u0, b.x) : 0.f;
      T[c16 + 4*i + 1][r] = v ? fmaf(a.y, u1v, b.y) : 0.f;
      T[c16 + 4*i + 2][r] = v ? fmaf(a.z, u2v, b.z) : 0.f;
      T[c16 + 4*i + 3][r] = v ? fmaf(a.w, u3v, b.w) : 0.f;
    }
  }
  __syncthreads();
  {
    const int ch = tid >> 2;
    const int m16 = (tid & 3) << 4;
    #pragma unroll
    for (int i = 0; i < 4; i++){
      int nn = n0 + m16 + 4*i;
      if (nn < N)
        *(float4*)(out + (size_t)(256 + ch) * N + nn) = *(const float4*)(&T[ch][m16 + 4*i]);
    }
  }
}

// ---------------- Fill glob rows (sum/combine the ncopy stat copies)
__global__ __launch_bounds__(256) void k_fill(
    const float* __restrict__ gS, const float* __restrict__ gQ,
    const int* __restrict__ gMx, const int* __restrict__ gMn,
    const float* __restrict__ g5, const float* __restrict__ be5,
    float* __restrict__ out, int ncopy, float invN, int N)
{
  const int c = blockIdx.y;
  const float FINF = __int_as_float(0x7f800000);
  float s = 0.f, q = 0.f, zx = 0.f, zn = FINF;
  for (int cp = 0; cp < ncopy; cp++){
    s += gS[cp*STS + c]; q += gQ[cp*STS + c];
    zx = fmaxf(zx, __int_as_float(gMx[cp*STS + c]));
    zn = fminf(zn, __int_as_float(gMn[cp*STS + c]));
  }
  float m = s * invN;
  float v = q * invN - m * m;
  float a = g5[c] * rsqrtf(v + EPSV);
  float d = fmaf(-a, m, be5[c]);
  float glob = (a >= 0.f) ? fmaf(a, zx, d) : fmaf(a, zn, d);
  int n0 = (blockIdx.x * 256 + threadIdx.x) * 8;
  float4 gv = make_float4(glob, glob, glob, glob);
  if (n0 < N)     *(float4*)(out + (size_t)c * N + n0)     = gv;
  if (n0 + 4 < N) *(float4*)(out + (size_t)c * N + n0 + 4) = gv;
}

extern "C" void kernel_launch(void* const* d_in, const int* in_sizes, int n_in,
                              void* d_out, int out_size, void* d_ws, size_t ws_size,
                              hipStream_t stream) {
  const int N = in_sizes[0] / 10;
  auto F = [&](int i){ return (const float*)d_in[i]; };
  const float* P  = F(0);
  const float* F1 = F(1); const float* F2 = F(2); const float* F3 = F(3); const float* F4 = F(4);
  const float* Wc1 = F(5);  const float* Bc1 = F(6);
  const float* Wc2 = F(7);  const float* Bc2 = F(8);
  const float* Wc3 = F(9);  const float* Bc3 = F(10);
  const float* Wc4 = F(11); const float* Bc4 = F(12);
  const float* Wc5 = F(13); const float* Bc5 = F(14);
  const float* G1 = F(15); const float* BE1 = F(16);
  const float* G2 = F(17); const float* BE2 = F(18);
  const float* G3 = F(19); const float* BE3 = F(20);
  const float* G4 = F(21); const float* BE4 = F(22);
  const float* G5 = F(23); const float* BE5 = F(24);
  const float *W2d1=F(25), *B2d1=F(26), *W3d1=F(27), *B3d1=F(28), *Wat1=F(29), *Bat1=F(30);
  const float *W2d2=F(31), *B2d2=F(32), *W3d2=F(33), *B3d2=F(34), *Wat2=F(35), *Bat2=F(36);
  const float *W2d3=F(37), *B2d3=F(38), *W3d3=F(39), *B3d3=F(40), *Wat3=F(41), *Bat3=F(42);
  const float *W2d4=F(43), *B2d4=F(44), *W3d4=F(45), *B3d4=F(46), *Wat4=F(47), *Bat4=F(48);

  float* out = (float*)d_out;
  // Scratch aliased into the glob region of the output (rows 0..255 = 256N floats, written last by k_fill).
  // CORRECTED layout (R4 bug: u2 is 16N floats, not 8N):
  float* u1 = out;                                                 // [N,16] fp32: floats [0,16N)
  unsigned short* u2 = (unsigned short*)(out + (size_t)N * 16);    // [N,32] f16:  floats [16N,32N)
  unsigned short* u3 = (unsigned short*)(out + (size_t)N * 32);    // [N,64] f16:  floats [32N,64N)
  unsigned short* u4 = (unsigned short*)(out + (size_t)N * 64);    // [N,128] bf16: floats [64N,128N)

  // d_ws layout: bf16+f16 weights [0,110592) bytes, then ncopy stat copies of STS floats.
  unsigned short* wbf = (unsigned short*)d_ws;
  float* st = (float*)((char*)d_ws + 110592);
  const int ncopy = (ws_size >= (size_t)110592 + 8u * STS * sizeof(float)) ? 8 : 1;
  float* S1 = st;        float* Q1 = st + 16;
  float* S2 = st + 32;   float* Q2 = st + 64;
  float* S3 = st + 96;   float* Q3 = st + 160;
  float* S4 = st + 224;  float* Q4 = st + 352;
  float* S5 = st + 480;  float* Q5 = st + 736;
  int*   MX = (int*)(st + 992);
  int*   MN = (int*)(st + 1248);
  hipMemsetAsync(st, 0, (size_t)ncopy * STS * sizeof(float), stream);
  for (int c = 0; c < ncopy; c++)
    hipMemsetAsync(MN + c * STS, 0x7f, 256 * sizeof(float), stream);  // +large float

  const int nb = (N + 255) / 256;
  const int nb64 = (N + 63) / 64;
  const float invN = 1.0f / (float)N;
  int NB1 = 1024; if (NB1 > nb) NB1 = nb;
  int NB2 = 1024; if (NB2 > nb64) NB2 = nb64;
  int NB3 = 768;  if (NB3 > nb64) NB3 = nb64;
  int NB4 = 768;  if (NB4 > nb64) NB4 = nb64;
  int NB5 = 1024; if (NB5 > nb64) NB5 = nb64;
  if (NB1 < 1) NB1 = 1; if (NB2 < 1) NB2 = 1; if (NB3 < 1) NB3 = 1;
  if (NB4 < 1) NB4 = 1; if (NB5 < 1) NB5 = 1;

  k_wprep<<<48, 256, 0, stream>>>(Wc4, W2d4, W3d4, Wat4, Wc5, wbf);
  k_wprep2<<<1, 256, 0, stream>>>(Wc2, W2d2, W3d2, Wat2, Wc3, W2d3, W3d3, Wat3, wbf);
  k_stage1<<<NB1, 256, 0, stream>>>(P, F1, Wc1, Bc1, W2d1, B2d1, W3d1, B3d1, Wat1, Bat1,
                                    u1, S1, Q1, ncopy, N);
  k_stage2_mfma<<<NB2, 256, 0, stream>>>(u1, S1, Q1, G1, BE1, F2, wbf + 49152,
                                         Bc2, B2d2, B3d2, Bat2,
                                         u2, S2, Q2, ncopy, invN, N);
  k_stage3_mfma<<<NB3, 256, 0, stream>>>(u2, S2, Q2, G2, BE2, F3, wbf + 51200,
                                         Bc3, B2d3, B3d3, Bat3,
                                         u3, S3, Q3, ncopy, invN, N);
  k_pf<<<nb64, 256, 0, stream>>>(u3, S3, Q3, G3, BE3, out, ncopy, invN, N);
  k_stage4_mfma<<<NB4, 256, 0, stream>>>(u3, S3, Q3, G3, BE3, F4, wbf,
                                         Bc4, B2d4, B3d4, Bat4,
                                         u4, S4, Q4, ncopy, invN, N);
  k_stage5_mfma<<<NB5, 256, 0, stream>>>(u4, S4, Q4, G4, BE4, wbf + 16384, Bc5,
                                         S5, Q5, MX, MN, ncopy, invN, N);
  dim3 gfill((N / 8 + 255) / 256, 256, 1);
  k_fill<<<gfill, 256, 0, stream>>>(S5, Q5, MX, MN, G5, BE5, out, ncopy, invN, N);
}